// Round 15
// baseline (236.756 us; speedup 1.0000x reference)
//
#include <hip/hip_runtime.h>

#define DD 128
#define HH 8
#define NBCOPY 32
#define PADS 4  // counters padded to 16 ints = 64B line

typedef float f32x4 __attribute__((ext_vector_type(4)));
typedef float f32x2 __attribute__((ext_vector_type(2)));
typedef short s16x8 __attribute__((ext_vector_type(8)));

__device__ __forceinline__ ushort f2b(float f) {
  unsigned u = __float_as_uint(f);
  unsigned r = u + 0x7fffu + ((u >> 16) & 1u);
  return (ushort)(r >> 16);
}
__device__ __forceinline__ float b2f(ushort b) {
  return __uint_as_float(((unsigned)b) << 16);
}
__device__ __forceinline__ void atomAddF(float* p, float v) {
#if defined(__HIP_DEVICE_COMPILE__)
  unsafeAtomicAdd(p, v);
#else
  atomicAdd(p, v);
#endif
}
__device__ __forceinline__ float lrelu(float v) { return fmaxf(v, 0.2f * v); }
__device__ __forceinline__ float4 u2f4(ushort4 v) {
  return make_float4(b2f(v.x), b2f(v.y), b2f(v.z), b2f(v.w));
}

__device__ __forceinline__ float sumC(const float* __restrict__ b8, int idx) {
  float s = 0.f;
#pragma unroll
  for (int c = 0; c < NBCOPY; c++) s += b8[(c << 8) + idx];
  return s;
}

// pack W[k][n] (128x128 row-major) into B-fragment order for 16x16x32 MFMA:
// P[((q*8+c)*64 + l)*8 + j] = W[q*32 + (l>>4)*8 + j][c*16 + (l&15)]
__device__ __forceinline__ void packW_idx(int i, int& k, int& n) {
  int j = i & 7, l = (i >> 3) & 63, tile = i >> 9;
  int q = tile >> 3, c = tile & 7;
  k = q * 32 + ((l >> 4) << 3) + j;
  n = c * 16 + (l & 15);
}

// ---------- fused prep: x->bf16 conv, Wl/Wr pack, degree histogram ----------
__global__ __launch_bounds__(256) void k_prep(const float* __restrict__ x,
    ushort* __restrict__ xb, int total4, const float* __restrict__ Wl,
    const float* __restrict__ Wr, ushort* __restrict__ WlP,
    ushort* __restrict__ WrP, const int* __restrict__ ei,
    int* __restrict__ deg, int E, int convB, int packB) {
  int b = blockIdx.x;
  if (b < convB) {
    int i = b * 256 + threadIdx.x;
    if (i < total4) {
      float4 v = ((const float4*)x)[i];
      ushort4 o;
      o.x = f2b(v.x); o.y = f2b(v.y); o.z = f2b(v.z); o.w = f2b(v.w);
      ((ushort4*)xb)[i] = o;
    }
  } else if (b < convB + packB) {
    int t = (b - convB) * 256 + threadIdx.x;  // 0..32767
    int side = t >> 14;
    int i = t & 16383;
    int k, n;
    packW_idx(i, k, n);
    if (side) WrP[i] = f2b(Wr[k * DD + n]);
    else      WlP[i] = f2b(Wl[k * DD + n]);
  } else {
    int e = (b - convB - packB) * 256 + threadIdx.x;
    if (e < E) atomicAdd(&deg[ei[E + e] << PADS], 1);
  }
}

// ---------- CSR scan (deg padded) ----------
__global__ __launch_bounds__(256) void k_part(const int* __restrict__ deg,
    int* __restrict__ rowstart, int* __restrict__ bsum, int N) {
  __shared__ int sc[256];
  int t = threadIdx.x;
  int i = blockIdx.x * 256 + t;
  int v = (i < N) ? deg[i << PADS] : 0;
  sc[t] = v;
  __syncthreads();
  for (int off = 1; off < 256; off <<= 1) {
    int u = (t >= off) ? sc[t - off] : 0;
    __syncthreads();
    sc[t] += u;
    __syncthreads();
  }
  if (i < N) rowstart[i] = sc[t] - v;
  if (t == 255) bsum[blockIdx.x] = sc[255];
}

// apply: each block sums its bsum prefix itself (B <= ~200, trivial)
__global__ __launch_bounds__(256) void k_apply(int* __restrict__ rowstart,
    int* __restrict__ cursor, const int* __restrict__ bsum, int N, int E) {
  __shared__ int red[256];
  int t = threadIdx.x;
  int acc = 0;
  for (int j = t; j < (int)blockIdx.x; j += 256) acc += bsum[j];
  red[t] = acc;
  __syncthreads();
  for (int off = 128; off; off >>= 1) {
    if (t < off) red[t] += red[t + off];
    __syncthreads();
  }
  int boff = red[0];
  int i = blockIdx.x * 256 + t;
  if (i < N) {
    int r = rowstart[i] + boff;
    rowstart[i] = r;
    cursor[i << PADS] = r;
  }
  if (blockIdx.x == 0 && t == 0) rowstart[N] = E;
}

// ---------- fused: mm_lr (MFMA, weights from L2) + csr fill (sd + pose) ----
__global__ __launch_bounds__(256) void k_lrfill(const ushort* __restrict__ xb,
    const ushort* __restrict__ WlP, const ushort* __restrict__ WrP,
    const float* __restrict__ bl, const float* __restrict__ br,
    ushort* __restrict__ xlb, ushort* __restrict__ xrb, int N, int mmB,
    const int* __restrict__ ei, int* __restrict__ cursor,
    int2* __restrict__ csr_sd, int* __restrict__ pose, int E) {
  if ((int)blockIdx.x >= mmB) {
    int e = ((int)blockIdx.x - mmB) * 256 + threadIdx.x;
    if (e < E) {
      int d = ei[E + e];
      int pos = atomicAdd(&cursor[d << PADS], 1);
      csr_sd[pos] = make_int2(ei[e], d);
      pose[e] = pos;
    }
    return;
  }
  int lane = threadIdx.x & 63;
  int wv = threadIdx.x >> 6;
  int rbase = blockIdx.x * 64 + wv * 16;
  int arow = rbase + (lane & 15);
  if (arow >= N) arow = 0;  // stores masked below
  const ushort* ap = xb + (size_t)arow * DD + ((lane >> 4) << 3);
  s16x8 afr[4];
#pragma unroll
  for (int q = 0; q < 4; q++) afr[q] = *(const s16x8*)(ap + q * 32);
  const s16x8* BL = (const s16x8*)WlP;
  const s16x8* BR = (const s16x8*)WrP;
  f32x4 accL[8] = {}, accR[8] = {};
#pragma unroll
  for (int q = 0; q < 4; q++) {
#pragma unroll
    for (int c = 0; c < 8; c++) {
      accL[c] = __builtin_amdgcn_mfma_f32_16x16x32_bf16(
          afr[q], BL[(q * 8 + c) * 64 + lane], accL[c], 0, 0, 0);
      accR[c] = __builtin_amdgcn_mfma_f32_16x16x32_bf16(
          afr[q], BR[(q * 8 + c) * 64 + lane], accR[c], 0, 0, 0);
    }
  }
  int r0 = rbase + ((lane >> 4) << 2);
  int colb = lane & 15;
#pragma unroll
  for (int c = 0; c < 8; c++) {
    int col = c * 16 + colb;
    float vbl = bl[col], vbr = br[col];
#pragma unroll
    for (int r = 0; r < 4; r++) {
      int row = r0 + r;
      if (row < N) {
        xlb[(size_t)row * DD + col] = f2b(accL[c][r] + vbl);
        xrb[(size_t)row * DD + col] = f2b(accR[c][r] + vbr);
      }
    }
  }
}

// ---------- GAT aggregation: 2 nodes/wave, 8-state pipeline + BN stats -----
// fixed-ref softmax exp(t - t_self); head = 4-lane group (2-level butterfly).
__global__ __launch_bounds__(256) void k_agg(const ushort* __restrict__ xlb,
    const ushort* __restrict__ xrb, const int* __restrict__ rowstart,
    const int2* __restrict__ csr_sd, const float* __restrict__ att,
    const float* __restrict__ cb, ushort* __restrict__ hfb,
    float* __restrict__ bnsumC, int N) {
  int lane = threadIdx.x & 63;
  int q = lane & 31;    // channel quad: ch 4q..4q+3 (mod 128)
  int h = lane >> 5;    // node within pair
  int wv = threadIdx.x >> 6;
  int pr = (blockIdx.x * 256 + threadIdx.x) >> 6;  // wave id = pair id
  int d = pr * 2 + h;
  bool active = d < N;
  int dc = active ? d : 0;
  float4 a = ((const float4*)att)[q];
  float4 c4 = ((const float4*)cb)[q];
  float4 out = make_float4(0.f, 0.f, 0.f, 0.f);
  {
    float4 r = u2f4(((const ushort4*)(xrb + (size_t)dc * DD))[q]);
    float4 g0 = u2f4(((const ushort4*)(xlb + (size_t)dc * DD))[q]);
    float t0 = lrelu(g0.x + r.x) * a.x + lrelu(g0.y + r.y) * a.y +
               lrelu(g0.z + r.z) * a.z + lrelu(g0.w + r.w) * a.w;
    t0 += __shfl_xor(t0, 1);
    t0 += __shfl_xor(t0, 2);
    float m0 = t0;
    float dn0 = 1.f, dn1 = 0.f, dn2 = 0.f, dn3 = 0.f;
    float dn4 = 0.f, dn5 = 0.f, dn6 = 0.f, dn7 = 0.f;
    float4 ac0 = g0;
    float4 ac1 = make_float4(0.f, 0.f, 0.f, 0.f);
    float4 ac2 = make_float4(0.f, 0.f, 0.f, 0.f);
    float4 ac3 = make_float4(0.f, 0.f, 0.f, 0.f);
    float4 ac4 = make_float4(0.f, 0.f, 0.f, 0.f);
    float4 ac5 = make_float4(0.f, 0.f, 0.f, 0.f);
    float4 ac6 = make_float4(0.f, 0.f, 0.f, 0.f);
    float4 ac7 = make_float4(0.f, 0.f, 0.f, 0.f);
    int i0 = rowstart[dc], i1 = active ? rowstart[dc + 1] : i0;
    int i = i0;
    for (; i + 8 <= i1; i += 8) {
      int s0 = csr_sd[i].x,     s1 = csr_sd[i + 1].x;
      int s2 = csr_sd[i + 2].x, s3 = csr_sd[i + 3].x;
      int s4 = csr_sd[i + 4].x, s5 = csr_sd[i + 5].x;
      int s6 = csr_sd[i + 6].x, s7 = csr_sd[i + 7].x;
      float4 ga = u2f4(((const ushort4*)(xlb + (size_t)s0 * DD))[q]);
      float4 gb = u2f4(((const ushort4*)(xlb + (size_t)s1 * DD))[q]);
      float4 gc = u2f4(((const ushort4*)(xlb + (size_t)s2 * DD))[q]);
      float4 gd = u2f4(((const ushort4*)(xlb + (size_t)s3 * DD))[q]);
      float4 ge = u2f4(((const ushort4*)(xlb + (size_t)s4 * DD))[q]);
      float4 gf = u2f4(((const ushort4*)(xlb + (size_t)s5 * DD))[q]);
      float4 gg = u2f4(((const ushort4*)(xlb + (size_t)s6 * DD))[q]);
      float4 gh = u2f4(((const ushort4*)(xlb + (size_t)s7 * DD))[q]);
      float ta = lrelu(ga.x + r.x) * a.x + lrelu(ga.y + r.y) * a.y +
                 lrelu(ga.z + r.z) * a.z + lrelu(ga.w + r.w) * a.w;
      float tb = lrelu(gb.x + r.x) * a.x + lrelu(gb.y + r.y) * a.y +
                 lrelu(gb.z + r.z) * a.z + lrelu(gb.w + r.w) * a.w;
      float tc = lrelu(gc.x + r.x) * a.x + lrelu(gc.y + r.y) * a.y +
                 lrelu(gc.z + r.z) * a.z + lrelu(gc.w + r.w) * a.w;
      float td = lrelu(gd.x + r.x) * a.x + lrelu(gd.y + r.y) * a.y +
                 lrelu(gd.z + r.z) * a.z + lrelu(gd.w + r.w) * a.w;
      float te = lrelu(ge.x + r.x) * a.x + lrelu(ge.y + r.y) * a.y +
                 lrelu(ge.z + r.z) * a.z + lrelu(ge.w + r.w) * a.w;
      float tf = lrelu(gf.x + r.x) * a.x + lrelu(gf.y + r.y) * a.y +
                 lrelu(gf.z + r.z) * a.z + lrelu(gf.w + r.w) * a.w;
      float tg = lrelu(gg.x + r.x) * a.x + lrelu(gg.y + r.y) * a.y +
                 lrelu(gg.z + r.z) * a.z + lrelu(gg.w + r.w) * a.w;
      float th = lrelu(gh.x + r.x) * a.x + lrelu(gh.y + r.y) * a.y +
                 lrelu(gh.z + r.z) * a.z + lrelu(gh.w + r.w) * a.w;
      ta += __shfl_xor(ta, 1); tb += __shfl_xor(tb, 1);
      tc += __shfl_xor(tc, 1); td += __shfl_xor(td, 1);
      te += __shfl_xor(te, 1); tf += __shfl_xor(tf, 1);
      tg += __shfl_xor(tg, 1); th += __shfl_xor(th, 1);
      ta += __shfl_xor(ta, 2); tb += __shfl_xor(tb, 2);
      tc += __shfl_xor(tc, 2); td += __shfl_xor(td, 2);
      te += __shfl_xor(te, 2); tf += __shfl_xor(tf, 2);
      tg += __shfl_xor(tg, 2); th += __shfl_xor(th, 2);
      float ea = __expf(fminf(ta - m0, 60.f));
      float eb = __expf(fminf(tb - m0, 60.f));
      float ec = __expf(fminf(tc - m0, 60.f));
      float ed = __expf(fminf(td - m0, 60.f));
      float ee = __expf(fminf(te - m0, 60.f));
      float ef = __expf(fminf(tf - m0, 60.f));
      float eg = __expf(fminf(tg - m0, 60.f));
      float eh = __expf(fminf(th - m0, 60.f));
      dn0 += ea;
      ac0.x += ea * ga.x; ac0.y += ea * ga.y;
      ac0.z += ea * ga.z; ac0.w += ea * ga.w;
      dn1 += eb;
      ac1.x += eb * gb.x; ac1.y += eb * gb.y;
      ac1.z += eb * gb.z; ac1.w += eb * gb.w;
      dn2 += ec;
      ac2.x += ec * gc.x; ac2.y += ec * gc.y;
      ac2.z += ec * gc.z; ac2.w += ec * gc.w;
      dn3 += ed;
      ac3.x += ed * gd.x; ac3.y += ed * gd.y;
      ac3.z += ed * gd.z; ac3.w += ed * gd.w;
      dn4 += ee;
      ac4.x += ee * ge.x; ac4.y += ee * ge.y;
      ac4.z += ee * ge.z; ac4.w += ee * ge.w;
      dn5 += ef;
      ac5.x += ef * gf.x; ac5.y += ef * gf.y;
      ac5.z += ef * gf.z; ac5.w += ef * gf.w;
      dn6 += eg;
      ac6.x += eg * gg.x; ac6.y += eg * gg.y;
      ac6.z += eg * gg.z; ac6.w += eg * gg.w;
      dn7 += eh;
      ac7.x += eh * gh.x; ac7.y += eh * gh.y;
      ac7.z += eh * gh.z; ac7.w += eh * gh.w;
    }
    for (; i < i1; i++) {
      int s = csr_sd[i].x;
      float4 ga = u2f4(((const ushort4*)(xlb + (size_t)s * DD))[q]);
      float ta = lrelu(ga.x + r.x) * a.x + lrelu(ga.y + r.y) * a.y +
                 lrelu(ga.z + r.z) * a.z + lrelu(ga.w + r.w) * a.w;
      ta += __shfl_xor(ta, 1);
      ta += __shfl_xor(ta, 2);
      float ea = __expf(fminf(ta - m0, 60.f));
      dn0 += ea;
      ac0.x += ea * ga.x; ac0.y += ea * ga.y;
      ac0.z += ea * ga.z; ac0.w += ea * ga.w;
    }
    float den = (((dn0 + dn1) + (dn2 + dn3)) + ((dn4 + dn5) + (dn6 + dn7))) +
                1e-16f;
    float inv = 1.f / den;
    float ax = ((ac0.x + ac1.x) + (ac2.x + ac3.x)) +
               ((ac4.x + ac5.x) + (ac6.x + ac7.x));
    float ay = ((ac0.y + ac1.y) + (ac2.y + ac3.y)) +
               ((ac4.y + ac5.y) + (ac6.y + ac7.y));
    float az = ((ac0.z + ac1.z) + (ac2.z + ac3.z)) +
               ((ac4.z + ac5.z) + (ac6.z + ac7.z));
    float aw = ((ac0.w + ac1.w) + (ac2.w + ac3.w)) +
               ((ac4.w + ac5.w) + (ac6.w + ac7.w));
    if (active) {
      out.x = fmaxf(fmaf(ax, inv, c4.x), 0.f);
      out.y = fmaxf(fmaf(ay, inv, c4.y), 0.f);
      out.z = fmaxf(fmaf(az, inv, c4.z), 0.f);
      out.w = fmaxf(fmaf(aw, inv, c4.w), 0.f);
      ushort4 o4;
      o4.x = f2b(out.x); o4.y = f2b(out.y);
      o4.z = f2b(out.z); o4.w = f2b(out.w);
      ((ushort4*)(hfb + (size_t)dc * DD))[q] = o4;
    }
  }
  // BN stats: per-lane 4-channel sums; block reduce; 256 atomics/block
  __shared__ float4 red_s[4][64];
  __shared__ float4 red_q[4][64];
  red_s[wv][lane] = out;
  red_q[wv][lane] = make_float4(out.x * out.x, out.y * out.y,
                                out.z * out.z, out.w * out.w);
  __syncthreads();
  if (threadIdx.x < 32) {
    int qq = threadIdx.x;
    float sx = 0.f, sy = 0.f, sz = 0.f, sw = 0.f;
    float qx = 0.f, qy = 0.f, qz = 0.f, qw = 0.f;
#pragma unroll
    for (int w = 0; w < 4; w++) {
      float4 p0 = red_s[w][qq], p1 = red_s[w][qq + 32];
      sx += p0.x + p1.x; sy += p0.y + p1.y;
      sz += p0.z + p1.z; sw += p0.w + p1.w;
      float4 q0 = red_q[w][qq], q1 = red_q[w][qq + 32];
      qx += q0.x + q1.x; qy += q0.y + q1.y;
      qz += q0.z + q1.z; qw += q0.w + q1.w;
    }
    float* bs = bnsumC + ((blockIdx.x & (NBCOPY - 1)) << 8);
    atomAddF(&bs[4 * qq + 0], sx);
    atomAddF(&bs[4 * qq + 1], sy);
    atomAddF(&bs[4 * qq + 2], sz);
    atomAddF(&bs[4 * qq + 3], sw);
    atomAddF(&bs[DD + 4 * qq + 0], qx);
    atomAddF(&bs[DD + 4 * qq + 1], qy);
    atomAddF(&bs[DD + 4 * qq + 2], qz);
    atomAddF(&bs[DD + 4 * qq + 3], qw);
  }
}

// ---------- fused fold: BN scale/shift + b1'/b2'' + W1P/W2P packs ----------
__global__ __launch_bounds__(256) void k_fold(const float* __restrict__ bnsumC,
    const float* __restrict__ gamma, const float* __restrict__ beta,
    const float* __restrict__ linW, const float* __restrict__ linb,
    const float* __restrict__ dec2W, const float* __restrict__ dec2b,
    float* __restrict__ b1p, float* __restrict__ b2pp,
    ushort* __restrict__ W1P, ushort* __restrict__ W2P, int N) {
  int b = blockIdx.x;
  float invN = 1.f / (float)N;
  if (b == 0) {
    int t = threadIdx.x;
    __shared__ float sshift[DD], sb1[DD];
    if (t < DD) {
      float mean = sumC(bnsumC, t) * invN;
      float var = sumC(bnsumC, DD + t) * invN - mean * mean;
      float sc = gamma[t] / sqrtf(var + 1e-5f);
      sshift[t] = beta[t] - mean * sc;
    }
    __syncthreads();
    if (t < DD) {
      float b1 = linb[t];
#pragma unroll 8
      for (int k = 0; k < DD; k++) b1 += sshift[k] * linW[k * DD + t];
      b1p[t] = b1;
      sb1[t] = b1;
    }
    __syncthreads();
    if (t < DD) {
      float b2v = dec2b[t];
#pragma unroll 8
      for (int k = 0; k < DD; k++) b2v += sb1[k] * dec2W[k * DD + t];
      b2pp[t] = b2v;
    }
  } else if (b <= 64) {
    int i = (b - 1) * 256 + threadIdx.x;
    int k, n;
    packW_idx(i, k, n);
    float mean = sumC(bnsumC, k) * invN;
    float var = sumC(bnsumC, DD + k) * invN - mean * mean;
    float sc = gamma[k] / sqrtf(var + 1e-5f);
    float s = 0.f;
#pragma unroll 8
    for (int kk = 0; kk < DD; kk++) s += linW[k * DD + kk] * dec2W[kk * DD + n];
    W2P[i] = f2b(sc * s);
  } else {
    int i = (b - 65) * 256 + threadIdx.x;
    int k, n;
    packW_idx(i, k, n);
    float mean = sumC(bnsumC, k) * invN;
    float var = sumC(bnsumC, DD + k) * invN - mean * mean;
    float sc = gamma[k] / sqrtf(var + 1e-5f);
    W1P[i] = f2b(sc * linW[k * DD + n]);
  }
}

// ---------- MFMA GEMM: z (f32) + z8 (fp8, lane-permuted layout) ----------
__global__ __launch_bounds__(256) void k_mmz1(const ushort* __restrict__ hfb,
    const ushort* __restrict__ W1P, const float* __restrict__ b1p,
    float* __restrict__ z, unsigned char* __restrict__ z8, int N) {
  int lane = threadIdx.x & 63;
  int wv = threadIdx.x >> 6;
  int rbase = blockIdx.x * 64 + wv * 16;
  int arow = rbase + (lane & 15);
  if (arow >= N) arow = 0;
  const ushort* ap = hfb + (size_t)arow * DD + ((lane >> 4) << 3);
  s16x8 afr[4];
#pragma unroll
  for (int q = 0; q < 4; q++) afr[q] = *(const s16x8*)(ap + q * 32);
  const s16x8* B1 = (const s16x8*)W1P;
  f32x4 acc1[8] = {};
#pragma unroll
  for (int q = 0; q < 4; q++) {
#pragma unroll
    for (int c = 0; c < 8; c++) {
      acc1[c] = __builtin_amdgcn_mfma_f32_16x16x32_bf16(
          afr[q], B1[(q * 8 + c) * 64 + lane], acc1[c], 0, 0, 0);
    }
  }
  int r0 = rbase + ((lane >> 4) << 2);
  int colb = lane & 15;
  float vb[8];
#pragma unroll
  for (int c = 0; c < 8; c++) vb[c] = b1p[c * 16 + colb];
#pragma unroll
  for (int c = 0; c < 8; c++) {
    int col = c * 16 + colb;
#pragma unroll
    for (int r = 0; r < 4; r++) {
      int row = r0 + r;
      if (row < N) z[(size_t)row * DD + col] = acc1[c][r] + vb[c];
    }
  }
#pragma unroll
  for (int r = 0; r < 4; r++) {
    int row = r0 + r;
    int u01 = __builtin_amdgcn_cvt_pk_fp8_f32(acc1[0][r] + vb[0],
                                              acc1[1][r] + vb[1], 0, false);
    u01 = __builtin_amdgcn_cvt_pk_fp8_f32(acc1[2][r] + vb[2],
                                          acc1[3][r] + vb[3], u01, true);
    int u23 = __builtin_amdgcn_cvt_pk_fp8_f32(acc1[4][r] + vb[4],
                                              acc1[5][r] + vb[5], 0, false);
    u23 = __builtin_amdgcn_cvt_pk_fp8_f32(acc1[6][r] + vb[6],
                                          acc1[7][r] + vb[7], u23, true);
    if (row < N)
      *(uint2*)(z8 + (size_t)row * DD + colb * 8) =
          make_uint2((unsigned)u01, (unsigned)u23);
  }
}

// ---------- fused tail: v2 GEMM + edge decoder (fp8, 8 lanes/edge) ----------
__global__ __launch_bounds__(256) void k_v2edge(const ushort* __restrict__ hfb,
    const ushort* __restrict__ W2P, const float* __restrict__ b2pp,
    float* __restrict__ v2, int N, int v2B,
    const unsigned char* __restrict__ z8, const int2* __restrict__ csr_sd,
    const float* __restrict__ ae, const float* __restrict__ be,
    float* __restrict__ v1c, int E, int edgeB) {
  if ((int)blockIdx.x < v2B) {
    int lane = threadIdx.x & 63;
    int wv = threadIdx.x >> 6;
    int rbase = blockIdx.x * 64 + wv * 16;
    int arow = rbase + (lane & 15);
    if (arow >= N) arow = 0;
    const ushort* ap = hfb + (size_t)arow * DD + ((lane >> 4) << 3);
    s16x8 afr[4];
#pragma unroll
    for (int q = 0; q < 4; q++) afr[q] = *(const s16x8*)(ap + q * 32);
    const s16x8* B2 = (const s16x8*)W2P;
    f32x4 acc2[8] = {};
#pragma unroll
    for (int q = 0; q < 4; q++) {
#pragma unroll
      for (int c = 0; c < 8; c++) {
        acc2[c] = __builtin_amdgcn_mfma_f32_16x16x32_bf16(
            afr[q], B2[(q * 8 + c) * 64 + lane], acc2[c], 0, 0, 0);
      }
    }
    int r0 = rbase + ((lane >> 4) << 2);
    int colb = lane & 15;
#pragma unroll
    for (int c = 0; c < 8; c++) {
      int col = c * 16 + colb;
      float vb2 = b2pp[col];
#pragma unroll
      for (int r = 0; r < 4; r++) {
        int row = r0 + r;
        if (row < N) v2[(size_t)row * DD + col] = acc2[c][r] + vb2;
      }
    }
    return;
  }
  int lane = threadIdx.x & 63;
  int sub = lane >> 3;   // edge slot within octet (8 edges/wave-iter)
  int el = lane & 7;     // lane within edge (16 B each, row = 128 B)
  int wid = (((int)blockIdx.x - v2B) * 256 + threadIdx.x) >> 6;
  int nw = (edgeB * 256) >> 6;
  int nq = (E + 7) >> 3;
  float a = fmaxf(ae[0], 0.f), b = be[0];
  for (int q = wid; q < nq; q += nw) {
    int p = q * 8 + sub;
    bool ok = p < E;
    int pc = ok ? p : 0;
    int2 sd = csr_sd[pc];
    uint4 zsu = *(const uint4*)(z8 + (size_t)sd.x * DD + el * 16);
    uint4 zdu = *(const uint4*)(z8 + (size_t)sd.y * DD + el * 16);
    float v = 0.f;
    float t;
    f32x2 s, dtmp;
#pragma unroll
    for (int w = 0; w < 4; w++) {
      unsigned ws = (w == 0) ? zsu.x : (w == 1) ? zsu.y : (w == 2) ? zsu.z : zsu.w;
      unsigned wd = (w == 0) ? zdu.x : (w == 1) ? zdu.y : (w == 2) ? zdu.z : zdu.w;
      s = __builtin_amdgcn_cvt_pk_f32_fp8(ws, false);
      dtmp = __builtin_amdgcn_cvt_pk_f32_fp8(wd, false);
      t = s.x - dtmp.x; v += t * t;
      t = s.y - dtmp.y; v += t * t;
      s = __builtin_amdgcn_cvt_pk_f32_fp8(ws, true);
      dtmp = __builtin_amdgcn_cvt_pk_f32_fp8(wd, true);
      t = s.x - dtmp.x; v += t * t;
      t = s.y - dtmp.y; v += t * t;
    }
#pragma unroll
    for (int o = 4; o; o >>= 1) v += __shfl_xor(v, o);
    if (el == 0 && ok) v1c[p] = 1.f / (1.f + __expf(fmaf(a, v, b)));
  }
}

// ---------- remap: v1[e] = v1_csr[pose[e]] (sequential writes) ----------
__global__ __launch_bounds__(256) void k_remap(const float* __restrict__ v1c,
    const int* __restrict__ pose, float* __restrict__ v1, int E) {
  int e = blockIdx.x * 256 + threadIdx.x;
  if (e < E) v1[e] = v1c[pose[e]];
}

extern "C" void kernel_launch(void* const* d_in, const int* in_sizes, int n_in,
                              void* d_out, int out_size, void* d_ws, size_t ws_size,
                              hipStream_t stream) {
  const float* x = (const float*)d_in[0];
  const int* ei = (const int*)d_in[1];
  const float* Wl = (const float*)d_in[2];
  const float* bl = (const float*)d_in[3];
  const float* Wr = (const float*)d_in[4];
  const float* br = (const float*)d_in[5];
  const float* att = (const float*)d_in[6];
  const float* cb = (const float*)d_in[7];
  const float* gamma = (const float*)d_in[8];
  const float* beta = (const float*)d_in[9];
  const float* linW = (const float*)d_in[10];
  const float* linb = (const float*)d_in[11];
  const float* ae = (const float*)d_in[12];
  const float* be = (const float*)d_in[13];
  const float* dec2W = (const float*)d_in[14];
  const float* dec2b = (const float*)d_in[15];

  int N = in_sizes[0] / DD;
  int E = in_sizes[1] / 2;
  size_t ND = (size_t)N * DD;
  int B = (N + 255) / 256;

  char* wsb = (char*)d_ws;
  size_t o = 0;
  auto alloc = [&](size_t bytes) {
    void* p = wsb + o;
    o += (bytes + 15) & ~(size_t)15;
    return p;
  };
  ushort* xb  = (ushort*)alloc(ND * 2);
  ushort* xlb = (ushort*)alloc(ND * 2);
  ushort* xrb = (ushort*)alloc(ND * 2);
  ushort* hfb = (ushort*)alloc(ND * 2);
  unsigned char* z8 = (unsigned char*)alloc(ND);
  ushort* WlP = (ushort*)alloc(DD * DD * 2);
  ushort* WrP = (ushort*)alloc(DD * DD * 2);
  ushort* W1P = (ushort*)alloc(DD * DD * 2);
  ushort* W2P = (ushort*)alloc(DD * DD * 2);
  float* b1p   = (float*)alloc(DD * 4);
  float* b2pp  = (float*)alloc(DD * 4);
  // deg (padded) + bnsumC contiguous -> single memset
  int* deg       = (int*)alloc(((size_t)N << PADS) * 4 + 64);
  float* bnsumC  = (float*)alloc(NBCOPY * 2 * DD * 4);
  size_t clearBytes = (char*)(bnsumC + NBCOPY * 2 * DD) - (char*)deg;
  int* rowstart = (int*)alloc((size_t)(N + 1) * 4);
  int* cursor   = (int*)alloc(((size_t)N << PADS) * 4 + 64);
  int* bsum     = (int*)alloc((size_t)B * 4);
  int2* csr_sd  = (int2*)alloc((size_t)E * 8);
  int* pose     = (int*)alloc((size_t)E * 4);
  float* v1c    = (float*)alloc((size_t)E * 4);

  float* z = (float*)d_out;
  float* v1 = z + ND;
  float* v2 = v1 + E;

  hipMemsetAsync(deg, 0, clearBytes, stream);

  int total4 = (int)(ND / 4);
  int convB = (total4 + 255) / 256;
  int packB = 128;
  int degB = (E + 255) / 256;
  k_prep<<<convB + packB + degB, 256, 0, stream>>>(x, xb, total4, Wl, Wr, WlP,
                                                   WrP, ei, deg, E, convB, packB);
  k_part<<<B, 256, 0, stream>>>(deg, rowstart, bsum, N);
  k_apply<<<B, 256, 0, stream>>>(rowstart, cursor, bsum, N, E);
  int mmB = (N + 63) / 64;
  int fillB = (E + 255) / 256;
  k_lrfill<<<mmB + fillB, 256, 0, stream>>>(xb, WlP, WrP, bl, br, xlb, xrb, N,
                                            mmB, ei, cursor, csr_sd, pose, E);
  k_agg<<<(N + 7) / 8, 256, 0, stream>>>(xlb, xrb, rowstart, csr_sd, att, cb,
                                         hfb, bnsumC, N);
  k_fold<<<129, 256, 0, stream>>>(bnsumC, gamma, beta, linW, linb, dec2W,
                                  dec2b, b1p, b2pp, W1P, W2P, N);
  k_mmz1<<<(N + 63) / 64, 256, 0, stream>>>(hfb, W1P, b1p, z, z8, N);
  int v2B = (N + 63) / 64;
  int edgeB = 2048;
  k_v2edge<<<v2B + edgeB, 256, 0, stream>>>(hfb, W2P, b2pp, v2, N, v2B, z8,
                                            csr_sd, ae, be, v1c, E, edgeB);
  k_remap<<<(E + 255) / 256, 256, 0, stream>>>(v1c, pose, v1, E);
}

// Round 16
// 216.891 us; speedup vs baseline: 1.0916x; 1.0916x over previous
//
#include <hip/hip_runtime.h>

#define DD 128
#define HH 8
#define NBCOPY 32
#define PADS 4  // counters padded to 16 ints = 64B line

typedef float f32x4 __attribute__((ext_vector_type(4)));
typedef float f32x2 __attribute__((ext_vector_type(2)));
typedef short s16x8 __attribute__((ext_vector_type(8)));

__device__ __forceinline__ ushort f2b(float f) {
  unsigned u = __float_as_uint(f);
  unsigned r = u + 0x7fffu + ((u >> 16) & 1u);
  return (ushort)(r >> 16);
}
__device__ __forceinline__ float b2f(ushort b) {
  return __uint_as_float(((unsigned)b) << 16);
}
__device__ __forceinline__ void atomAddF(float* p, float v) {
#if defined(__HIP_DEVICE_COMPILE__)
  unsafeAtomicAdd(p, v);
#else
  atomicAdd(p, v);
#endif
}
__device__ __forceinline__ float lrelu(float v) { return fmaxf(v, 0.2f * v); }
__device__ __forceinline__ float4 u2f4(ushort4 v) {
  return make_float4(b2f(v.x), b2f(v.y), b2f(v.z), b2f(v.w));
}

__device__ __forceinline__ float sumC(const float* __restrict__ b8, int idx) {
  float s = 0.f;
#pragma unroll
  for (int c = 0; c < NBCOPY; c++) s += b8[(c << 8) + idx];
  return s;
}

// pack W[k][n] (128x128 row-major) into B-fragment order for 16x16x32 MFMA:
// P[((q*8+c)*64 + l)*8 + j] = W[q*32 + (l>>4)*8 + j][c*16 + (l&15)]
__device__ __forceinline__ void packW_idx(int i, int& k, int& n) {
  int j = i & 7, l = (i >> 3) & 63, tile = i >> 9;
  int q = tile >> 3, c = tile & 7;
  k = q * 32 + ((l >> 4) << 3) + j;
  n = c * 16 + (l & 15);
}

// ---------- fused prep: x->bf16 conv, Wl/Wr pack, degree histogram ----------
__global__ __launch_bounds__(256) void k_prep(const float* __restrict__ x,
    ushort* __restrict__ xb, int total4, const float* __restrict__ Wl,
    const float* __restrict__ Wr, ushort* __restrict__ WlP,
    ushort* __restrict__ WrP, const int* __restrict__ ei,
    int* __restrict__ deg, int E, int convB, int packB) {
  int b = blockIdx.x;
  if (b < convB) {
    int i = b * 256 + threadIdx.x;
    if (i < total4) {
      float4 v = ((const float4*)x)[i];
      ushort4 o;
      o.x = f2b(v.x); o.y = f2b(v.y); o.z = f2b(v.z); o.w = f2b(v.w);
      ((ushort4*)xb)[i] = o;
    }
  } else if (b < convB + packB) {
    int t = (b - convB) * 256 + threadIdx.x;  // 0..32767
    int side = t >> 14;
    int i = t & 16383;
    int k, n;
    packW_idx(i, k, n);
    if (side) WrP[i] = f2b(Wr[k * DD + n]);
    else      WlP[i] = f2b(Wl[k * DD + n]);
  } else {
    int e = (b - convB - packB) * 256 + threadIdx.x;
    if (e < E) atomicAdd(&deg[ei[E + e] << PADS], 1);
  }
}

// ---------- CSR scan (deg padded) ----------
__global__ __launch_bounds__(256) void k_part(const int* __restrict__ deg,
    int* __restrict__ rowstart, int* __restrict__ bsum, int N) {
  __shared__ int sc[256];
  int t = threadIdx.x;
  int i = blockIdx.x * 256 + t;
  int v = (i < N) ? deg[i << PADS] : 0;
  sc[t] = v;
  __syncthreads();
  for (int off = 1; off < 256; off <<= 1) {
    int u = (t >= off) ? sc[t - off] : 0;
    __syncthreads();
    sc[t] += u;
    __syncthreads();
  }
  if (i < N) rowstart[i] = sc[t] - v;
  if (t == 255) bsum[blockIdx.x] = sc[255];
}

// apply: each block sums its bsum prefix itself (B <= ~200, trivial)
__global__ __launch_bounds__(256) void k_apply(int* __restrict__ rowstart,
    int* __restrict__ cursor, const int* __restrict__ bsum, int N, int E) {
  __shared__ int red[256];
  int t = threadIdx.x;
  int acc = 0;
  for (int j = t; j < (int)blockIdx.x; j += 256) acc += bsum[j];
  red[t] = acc;
  __syncthreads();
  for (int off = 128; off; off >>= 1) {
    if (t < off) red[t] += red[t + off];
    __syncthreads();
  }
  int boff = red[0];
  int i = blockIdx.x * 256 + t;
  if (i < N) {
    int r = rowstart[i] + boff;
    rowstart[i] = r;
    cursor[i << PADS] = r;
  }
  if (blockIdx.x == 0 && t == 0) rowstart[N] = E;
}

// ---------- fused: mm_lr (MFMA, weights from L2) + csr fill (sd + pose) ----
__global__ __launch_bounds__(256) void k_lrfill(const ushort* __restrict__ xb,
    const ushort* __restrict__ WlP, const ushort* __restrict__ WrP,
    const float* __restrict__ bl, const float* __restrict__ br,
    ushort* __restrict__ xlb, ushort* __restrict__ xrb, int N, int mmB,
    const int* __restrict__ ei, int* __restrict__ cursor,
    int2* __restrict__ csr_sd, int* __restrict__ pose, int E) {
  if ((int)blockIdx.x >= mmB) {
    int e = ((int)blockIdx.x - mmB) * 256 + threadIdx.x;
    if (e < E) {
      int d = ei[E + e];
      int pos = atomicAdd(&cursor[d << PADS], 1);
      csr_sd[pos] = make_int2(ei[e], d);
      pose[e] = pos;
    }
    return;
  }
  int lane = threadIdx.x & 63;
  int wv = threadIdx.x >> 6;
  int rbase = blockIdx.x * 64 + wv * 16;
  int arow = rbase + (lane & 15);
  if (arow >= N) arow = 0;  // stores masked below
  const ushort* ap = xb + (size_t)arow * DD + ((lane >> 4) << 3);
  s16x8 afr[4];
#pragma unroll
  for (int q = 0; q < 4; q++) afr[q] = *(const s16x8*)(ap + q * 32);
  const s16x8* BL = (const s16x8*)WlP;
  const s16x8* BR = (const s16x8*)WrP;
  f32x4 accL[8] = {}, accR[8] = {};
#pragma unroll
  for (int q = 0; q < 4; q++) {
#pragma unroll
    for (int c = 0; c < 8; c++) {
      accL[c] = __builtin_amdgcn_mfma_f32_16x16x32_bf16(
          afr[q], BL[(q * 8 + c) * 64 + lane], accL[c], 0, 0, 0);
      accR[c] = __builtin_amdgcn_mfma_f32_16x16x32_bf16(
          afr[q], BR[(q * 8 + c) * 64 + lane], accR[c], 0, 0, 0);
    }
  }
  int r0 = rbase + ((lane >> 4) << 2);
  int colb = lane & 15;
#pragma unroll
  for (int c = 0; c < 8; c++) {
    int col = c * 16 + colb;
    float vbl = bl[col], vbr = br[col];
#pragma unroll
    for (int r = 0; r < 4; r++) {
      int row = r0 + r;
      if (row < N) {
        xlb[(size_t)row * DD + col] = f2b(accL[c][r] + vbl);
        xrb[(size_t)row * DD + col] = f2b(accR[c][r] + vbr);
      }
    }
  }
}

// ---------- GAT aggregation: 2 nodes/wave (32 lanes, 4ch/lane) + BN stats --
// fixed-ref softmax exp(t - t_self); head = 4-lane group (2-level butterfly).
__global__ __launch_bounds__(256) void k_agg(const ushort* __restrict__ xlb,
    const ushort* __restrict__ xrb, const int* __restrict__ rowstart,
    const int2* __restrict__ csr_sd, const float* __restrict__ att,
    const float* __restrict__ cb, ushort* __restrict__ hfb,
    float* __restrict__ bnsumC, int N) {
  int lane = threadIdx.x & 63;
  int q = lane & 31;    // channel quad: ch 4q..4q+3 (mod 128)
  int h = lane >> 5;    // node within pair
  int wv = threadIdx.x >> 6;
  int pr = (blockIdx.x * 256 + threadIdx.x) >> 6;  // wave id = pair id
  int d = pr * 2 + h;
  bool active = d < N;
  int dc = active ? d : 0;
  float4 a = ((const float4*)att)[q];
  float4 c4 = ((const float4*)cb)[q];
  float4 out = make_float4(0.f, 0.f, 0.f, 0.f);
  {
    float4 r = u2f4(((const ushort4*)(xrb + (size_t)dc * DD))[q]);
    float4 g0 = u2f4(((const ushort4*)(xlb + (size_t)dc * DD))[q]);
    float t0 = lrelu(g0.x + r.x) * a.x + lrelu(g0.y + r.y) * a.y +
               lrelu(g0.z + r.z) * a.z + lrelu(g0.w + r.w) * a.w;
    t0 += __shfl_xor(t0, 1);
    t0 += __shfl_xor(t0, 2);
    float m0 = t0;
    float den0 = 1.f, den1 = 0.f, den2 = 0.f, den3 = 0.f;
    float4 acc0 = g0;
    float4 acc1 = make_float4(0.f, 0.f, 0.f, 0.f);
    float4 acc2 = make_float4(0.f, 0.f, 0.f, 0.f);
    float4 acc3 = make_float4(0.f, 0.f, 0.f, 0.f);
    int i0 = rowstart[dc], i1 = active ? rowstart[dc + 1] : i0;
    int i = i0;
    for (; i + 4 <= i1; i += 4) {
      int s0 = csr_sd[i].x, s1 = csr_sd[i + 1].x;
      int s2 = csr_sd[i + 2].x, s3 = csr_sd[i + 3].x;
      float4 ga = u2f4(((const ushort4*)(xlb + (size_t)s0 * DD))[q]);
      float4 gb = u2f4(((const ushort4*)(xlb + (size_t)s1 * DD))[q]);
      float4 gc = u2f4(((const ushort4*)(xlb + (size_t)s2 * DD))[q]);
      float4 gd = u2f4(((const ushort4*)(xlb + (size_t)s3 * DD))[q]);
      float ta = lrelu(ga.x + r.x) * a.x + lrelu(ga.y + r.y) * a.y +
                 lrelu(ga.z + r.z) * a.z + lrelu(ga.w + r.w) * a.w;
      float tb = lrelu(gb.x + r.x) * a.x + lrelu(gb.y + r.y) * a.y +
                 lrelu(gb.z + r.z) * a.z + lrelu(gb.w + r.w) * a.w;
      float tc = lrelu(gc.x + r.x) * a.x + lrelu(gc.y + r.y) * a.y +
                 lrelu(gc.z + r.z) * a.z + lrelu(gc.w + r.w) * a.w;
      float td = lrelu(gd.x + r.x) * a.x + lrelu(gd.y + r.y) * a.y +
                 lrelu(gd.z + r.z) * a.z + lrelu(gd.w + r.w) * a.w;
      ta += __shfl_xor(ta, 1); tb += __shfl_xor(tb, 1);
      tc += __shfl_xor(tc, 1); td += __shfl_xor(td, 1);
      ta += __shfl_xor(ta, 2); tb += __shfl_xor(tb, 2);
      tc += __shfl_xor(tc, 2); td += __shfl_xor(td, 2);
      float ea = __expf(fminf(ta - m0, 60.f));
      float eb = __expf(fminf(tb - m0, 60.f));
      float ec = __expf(fminf(tc - m0, 60.f));
      float ed = __expf(fminf(td - m0, 60.f));
      den0 += ea;
      acc0.x += ea * ga.x; acc0.y += ea * ga.y;
      acc0.z += ea * ga.z; acc0.w += ea * ga.w;
      den1 += eb;
      acc1.x += eb * gb.x; acc1.y += eb * gb.y;
      acc1.z += eb * gb.z; acc1.w += eb * gb.w;
      den2 += ec;
      acc2.x += ec * gc.x; acc2.y += ec * gc.y;
      acc2.z += ec * gc.z; acc2.w += ec * gc.w;
      den3 += ed;
      acc3.x += ed * gd.x; acc3.y += ed * gd.y;
      acc3.z += ed * gd.z; acc3.w += ed * gd.w;
    }
    for (; i < i1; i++) {
      int s = csr_sd[i].x;
      float4 ga = u2f4(((const ushort4*)(xlb + (size_t)s * DD))[q]);
      float ta = lrelu(ga.x + r.x) * a.x + lrelu(ga.y + r.y) * a.y +
                 lrelu(ga.z + r.z) * a.z + lrelu(ga.w + r.w) * a.w;
      ta += __shfl_xor(ta, 1);
      ta += __shfl_xor(ta, 2);
      float ea = __expf(fminf(ta - m0, 60.f));
      den0 += ea;
      acc0.x += ea * ga.x; acc0.y += ea * ga.y;
      acc0.z += ea * ga.z; acc0.w += ea * ga.w;
    }
    float den = ((den0 + den1) + (den2 + den3)) + 1e-16f;
    float inv = 1.f / den;
    float ax = (acc0.x + acc1.x) + (acc2.x + acc3.x);
    float ay = (acc0.y + acc1.y) + (acc2.y + acc3.y);
    float az = (acc0.z + acc1.z) + (acc2.z + acc3.z);
    float aw = (acc0.w + acc1.w) + (acc2.w + acc3.w);
    if (active) {
      out.x = fmaxf(fmaf(ax, inv, c4.x), 0.f);
      out.y = fmaxf(fmaf(ay, inv, c4.y), 0.f);
      out.z = fmaxf(fmaf(az, inv, c4.z), 0.f);
      out.w = fmaxf(fmaf(aw, inv, c4.w), 0.f);
      ushort4 o4;
      o4.x = f2b(out.x); o4.y = f2b(out.y);
      o4.z = f2b(out.z); o4.w = f2b(out.w);
      ((ushort4*)(hfb + (size_t)dc * DD))[q] = o4;
    }
  }
  // BN stats: per-lane 4-channel sums; block reduce; 256 atomics/block
  __shared__ float4 red_s[4][64];
  __shared__ float4 red_q[4][64];
  red_s[wv][lane] = out;
  red_q[wv][lane] = make_float4(out.x * out.x, out.y * out.y,
                                out.z * out.z, out.w * out.w);
  __syncthreads();
  if (threadIdx.x < 32) {
    int qq = threadIdx.x;
    float sx = 0.f, sy = 0.f, sz = 0.f, sw = 0.f;
    float qx = 0.f, qy = 0.f, qz = 0.f, qw = 0.f;
#pragma unroll
    for (int w = 0; w < 4; w++) {
      float4 p0 = red_s[w][qq], p1 = red_s[w][qq + 32];
      sx += p0.x + p1.x; sy += p0.y + p1.y;
      sz += p0.z + p1.z; sw += p0.w + p1.w;
      float4 q0 = red_q[w][qq], q1 = red_q[w][qq + 32];
      qx += q0.x + q1.x; qy += q0.y + q1.y;
      qz += q0.z + q1.z; qw += q0.w + q1.w;
    }
    float* bs = bnsumC + ((blockIdx.x & (NBCOPY - 1)) << 8);
    atomAddF(&bs[4 * qq + 0], sx);
    atomAddF(&bs[4 * qq + 1], sy);
    atomAddF(&bs[4 * qq + 2], sz);
    atomAddF(&bs[4 * qq + 3], sw);
    atomAddF(&bs[DD + 4 * qq + 0], qx);
    atomAddF(&bs[DD + 4 * qq + 1], qy);
    atomAddF(&bs[DD + 4 * qq + 2], qz);
    atomAddF(&bs[DD + 4 * qq + 3], qw);
  }
}

// ---------- fused fold: BN scale/shift + b1'/b2'' + W1P/W2P packs ----------
__global__ __launch_bounds__(256) void k_fold(const float* __restrict__ bnsumC,
    const float* __restrict__ gamma, const float* __restrict__ beta,
    const float* __restrict__ linW, const float* __restrict__ linb,
    const float* __restrict__ dec2W, const float* __restrict__ dec2b,
    float* __restrict__ b1p, float* __restrict__ b2pp,
    ushort* __restrict__ W1P, ushort* __restrict__ W2P, int N) {
  int b = blockIdx.x;
  float invN = 1.f / (float)N;
  if (b == 0) {
    int t = threadIdx.x;
    __shared__ float sshift[DD], sb1[DD];
    if (t < DD) {
      float mean = sumC(bnsumC, t) * invN;
      float var = sumC(bnsumC, DD + t) * invN - mean * mean;
      float sc = gamma[t] / sqrtf(var + 1e-5f);
      sshift[t] = beta[t] - mean * sc;
    }
    __syncthreads();
    if (t < DD) {
      float b1 = linb[t];
#pragma unroll 8
      for (int k = 0; k < DD; k++) b1 += sshift[k] * linW[k * DD + t];
      b1p[t] = b1;
      sb1[t] = b1;
    }
    __syncthreads();
    if (t < DD) {
      float b2v = dec2b[t];
#pragma unroll 8
      for (int k = 0; k < DD; k++) b2v += sb1[k] * dec2W[k * DD + t];
      b2pp[t] = b2v;
    }
  } else if (b <= 64) {
    int i = (b - 1) * 256 + threadIdx.x;
    int k, n;
    packW_idx(i, k, n);
    float mean = sumC(bnsumC, k) * invN;
    float var = sumC(bnsumC, DD + k) * invN - mean * mean;
    float sc = gamma[k] / sqrtf(var + 1e-5f);
    float s = 0.f;
#pragma unroll 8
    for (int kk = 0; kk < DD; kk++) s += linW[k * DD + kk] * dec2W[kk * DD + n];
    W2P[i] = f2b(sc * s);
  } else {
    int i = (b - 65) * 256 + threadIdx.x;
    int k, n;
    packW_idx(i, k, n);
    float mean = sumC(bnsumC, k) * invN;
    float var = sumC(bnsumC, DD + k) * invN - mean * mean;
    float sc = gamma[k] / sqrtf(var + 1e-5f);
    W1P[i] = f2b(sc * linW[k * DD + n]);
  }
}

// ---------- MFMA GEMM: z (f32) + z8 (fp8, lane-permuted layout) ----------
__global__ __launch_bounds__(256) void k_mmz1(const ushort* __restrict__ hfb,
    const ushort* __restrict__ W1P, const float* __restrict__ b1p,
    float* __restrict__ z, unsigned char* __restrict__ z8, int N) {
  int lane = threadIdx.x & 63;
  int wv = threadIdx.x >> 6;
  int rbase = blockIdx.x * 64 + wv * 16;
  int arow = rbase + (lane & 15);
  if (arow >= N) arow = 0;
  const ushort* ap = hfb + (size_t)arow * DD + ((lane >> 4) << 3);
  s16x8 afr[4];
#pragma unroll
  for (int q = 0; q < 4; q++) afr[q] = *(const s16x8*)(ap + q * 32);
  const s16x8* B1 = (const s16x8*)W1P;
  f32x4 acc1[8] = {};
#pragma unroll
  for (int q = 0; q < 4; q++) {
#pragma unroll
    for (int c = 0; c < 8; c++) {
      acc1[c] = __builtin_amdgcn_mfma_f32_16x16x32_bf16(
          afr[q], B1[(q * 8 + c) * 64 + lane], acc1[c], 0, 0, 0);
    }
  }
  int r0 = rbase + ((lane >> 4) << 2);
  int colb = lane & 15;
  float vb[8];
#pragma unroll
  for (int c = 0; c < 8; c++) vb[c] = b1p[c * 16 + colb];
#pragma unroll
  for (int c = 0; c < 8; c++) {
    int col = c * 16 + colb;
#pragma unroll
    for (int r = 0; r < 4; r++) {
      int row = r0 + r;
      if (row < N) z[(size_t)row * DD + col] = acc1[c][r] + vb[c];
    }
  }
#pragma unroll
  for (int r = 0; r < 4; r++) {
    int row = r0 + r;
    int u01 = __builtin_amdgcn_cvt_pk_fp8_f32(acc1[0][r] + vb[0],
                                              acc1[1][r] + vb[1], 0, false);
    u01 = __builtin_amdgcn_cvt_pk_fp8_f32(acc1[2][r] + vb[2],
                                          acc1[3][r] + vb[3], u01, true);
    int u23 = __builtin_amdgcn_cvt_pk_fp8_f32(acc1[4][r] + vb[4],
                                              acc1[5][r] + vb[5], 0, false);
    u23 = __builtin_amdgcn_cvt_pk_fp8_f32(acc1[6][r] + vb[6],
                                          acc1[7][r] + vb[7], u23, true);
    if (row < N)
      *(uint2*)(z8 + (size_t)row * DD + colb * 8) =
          make_uint2((unsigned)u01, (unsigned)u23);
  }
}

// ---------- fused tail: v2 GEMM + edge decoder (fp8, 8 lanes/edge) ----------
__global__ __launch_bounds__(256) void k_v2edge(const ushort* __restrict__ hfb,
    const ushort* __restrict__ W2P, const float* __restrict__ b2pp,
    float* __restrict__ v2, int N, int v2B,
    const unsigned char* __restrict__ z8, const int2* __restrict__ csr_sd,
    const float* __restrict__ ae, const float* __restrict__ be,
    float* __restrict__ v1c, int E, int edgeB) {
  if ((int)blockIdx.x < v2B) {
    int lane = threadIdx.x & 63;
    int wv = threadIdx.x >> 6;
    int rbase = blockIdx.x * 64 + wv * 16;
    int arow = rbase + (lane & 15);
    if (arow >= N) arow = 0;
    const ushort* ap = hfb + (size_t)arow * DD + ((lane >> 4) << 3);
    s16x8 afr[4];
#pragma unroll
    for (int q = 0; q < 4; q++) afr[q] = *(const s16x8*)(ap + q * 32);
    const s16x8* B2 = (const s16x8*)W2P;
    f32x4 acc2[8] = {};
#pragma unroll
    for (int q = 0; q < 4; q++) {
#pragma unroll
      for (int c = 0; c < 8; c++) {
        acc2[c] = __builtin_amdgcn_mfma_f32_16x16x32_bf16(
            afr[q], B2[(q * 8 + c) * 64 + lane], acc2[c], 0, 0, 0);
      }
    }
    int r0 = rbase + ((lane >> 4) << 2);
    int colb = lane & 15;
#pragma unroll
    for (int c = 0; c < 8; c++) {
      int col = c * 16 + colb;
      float vb2 = b2pp[col];
#pragma unroll
      for (int r = 0; r < 4; r++) {
        int row = r0 + r;
        if (row < N) v2[(size_t)row * DD + col] = acc2[c][r] + vb2;
      }
    }
    return;
  }
  int lane = threadIdx.x & 63;
  int sub = lane >> 3;   // edge slot within octet (8 edges/wave-iter)
  int el = lane & 7;     // lane within edge (16 B each, row = 128 B)
  int wid = (((int)blockIdx.x - v2B) * 256 + threadIdx.x) >> 6;
  int nw = (edgeB * 256) >> 6;
  int nq = (E + 7) >> 3;
  float a = fmaxf(ae[0], 0.f), b = be[0];
  for (int q = wid; q < nq; q += nw) {
    int p = q * 8 + sub;
    bool ok = p < E;
    int pc = ok ? p : 0;
    int2 sd = csr_sd[pc];
    uint4 zsu = *(const uint4*)(z8 + (size_t)sd.x * DD + el * 16);
    uint4 zdu = *(const uint4*)(z8 + (size_t)sd.y * DD + el * 16);
    float v = 0.f;
    float t;
    f32x2 s, dtmp;
#pragma unroll
    for (int w = 0; w < 4; w++) {
      unsigned ws = (w == 0) ? zsu.x : (w == 1) ? zsu.y : (w == 2) ? zsu.z : zsu.w;
      unsigned wd = (w == 0) ? zdu.x : (w == 1) ? zdu.y : (w == 2) ? zdu.z : zdu.w;
      s = __builtin_amdgcn_cvt_pk_f32_fp8(ws, false);
      dtmp = __builtin_amdgcn_cvt_pk_f32_fp8(wd, false);
      t = s.x - dtmp.x; v += t * t;
      t = s.y - dtmp.y; v += t * t;
      s = __builtin_amdgcn_cvt_pk_f32_fp8(ws, true);
      dtmp = __builtin_amdgcn_cvt_pk_f32_fp8(wd, true);
      t = s.x - dtmp.x; v += t * t;
      t = s.y - dtmp.y; v += t * t;
    }
#pragma unroll
    for (int o = 4; o; o >>= 1) v += __shfl_xor(v, o);
    if (el == 0 && ok) v1c[p] = 1.f / (1.f + __expf(fmaf(a, v, b)));
  }
}

// ---------- remap: v1[e] = v1_csr[pose[e]] (sequential writes) ----------
__global__ __launch_bounds__(256) void k_remap(const float* __restrict__ v1c,
    const int* __restrict__ pose, float* __restrict__ v1, int E) {
  int e = blockIdx.x * 256 + threadIdx.x;
  if (e < E) v1[e] = v1c[pose[e]];
}

extern "C" void kernel_launch(void* const* d_in, const int* in_sizes, int n_in,
                              void* d_out, int out_size, void* d_ws, size_t ws_size,
                              hipStream_t stream) {
  const float* x = (const float*)d_in[0];
  const int* ei = (const int*)d_in[1];
  const float* Wl = (const float*)d_in[2];
  const float* bl = (const float*)d_in[3];
  const float* Wr = (const float*)d_in[4];
  const float* br = (const float*)d_in[5];
  const float* att = (const float*)d_in[6];
  const float* cb = (const float*)d_in[7];
  const float* gamma = (const float*)d_in[8];
  const float* beta = (const float*)d_in[9];
  const float* linW = (const float*)d_in[10];
  const float* linb = (const float*)d_in[11];
  const float* ae = (const float*)d_in[12];
  const float* be = (const float*)d_in[13];
  const float* dec2W = (const float*)d_in[14];
  const float* dec2b = (const float*)d_in[15];

  int N = in_sizes[0] / DD;
  int E = in_sizes[1] / 2;
  size_t ND = (size_t)N * DD;
  int B = (N + 255) / 256;

  char* wsb = (char*)d_ws;
  size_t o = 0;
  auto alloc = [&](size_t bytes) {
    void* p = wsb + o;
    o += (bytes + 15) & ~(size_t)15;
    return p;
  };
  ushort* xb  = (ushort*)alloc(ND * 2);
  ushort* xlb = (ushort*)alloc(ND * 2);
  ushort* xrb = (ushort*)alloc(ND * 2);
  ushort* hfb = (ushort*)alloc(ND * 2);
  unsigned char* z8 = (unsigned char*)alloc(ND);
  ushort* WlP = (ushort*)alloc(DD * DD * 2);
  ushort* WrP = (ushort*)alloc(DD * DD * 2);
  ushort* W1P = (ushort*)alloc(DD * DD * 2);
  ushort* W2P = (ushort*)alloc(DD * DD * 2);
  float* b1p   = (float*)alloc(DD * 4);
  float* b2pp  = (float*)alloc(DD * 4);
  // deg (padded) + bnsumC contiguous -> single memset
  int* deg       = (int*)alloc(((size_t)N << PADS) * 4 + 64);
  float* bnsumC  = (float*)alloc(NBCOPY * 2 * DD * 4);
  size_t clearBytes = (char*)(bnsumC + NBCOPY * 2 * DD) - (char*)deg;
  int* rowstart = (int*)alloc((size_t)(N + 1) * 4);
  int* cursor   = (int*)alloc(((size_t)N << PADS) * 4 + 64);
  int* bsum     = (int*)alloc((size_t)B * 4);
  int2* csr_sd  = (int2*)alloc((size_t)E * 8);
  int* pose     = (int*)alloc((size_t)E * 4);
  float* v1c    = (float*)alloc((size_t)E * 4);

  float* z = (float*)d_out;
  float* v1 = z + ND;
  float* v2 = v1 + E;

  hipMemsetAsync(deg, 0, clearBytes, stream);

  int total4 = (int)(ND / 4);
  int convB = (total4 + 255) / 256;
  int packB = 128;
  int degB = (E + 255) / 256;
  k_prep<<<convB + packB + degB, 256, 0, stream>>>(x, xb, total4, Wl, Wr, WlP,
                                                   WrP, ei, deg, E, convB, packB);
  k_part<<<B, 256, 0, stream>>>(deg, rowstart, bsum, N);
  k_apply<<<B, 256, 0, stream>>>(rowstart, cursor, bsum, N, E);
  int mmB = (N + 63) / 64;
  int fillB = (E + 255) / 256;
  k_lrfill<<<mmB + fillB, 256, 0, stream>>>(xb, WlP, WrP, bl, br, xlb, xrb, N,
                                            mmB, ei, cursor, csr_sd, pose, E);
  k_agg<<<(N + 7) / 8, 256, 0, stream>>>(xlb, xrb, rowstart, csr_sd, att, cb,
                                         hfb, bnsumC, N);
  k_fold<<<129, 256, 0, stream>>>(bnsumC, gamma, beta, linW, linb, dec2W,
                                  dec2b, b1p, b2pp, W1P, W2P, N);
  k_mmz1<<<(N + 63) / 64, 256, 0, stream>>>(hfb, W1P, b1p, z, z8, N);
  int v2B = (N + 63) / 64;
  int edgeB = 2048;
  k_v2edge<<<v2B + edgeB, 256, 0, stream>>>(hfb, W2P, b2pp, v2, N, v2B, z8,
                                            csr_sd, ae, be, v1c, E, edgeB);
  k_remap<<<(E + 255) / 256, 256, 0, stream>>>(v1c, pose, v1, E);
}